// Round 1
// baseline (298.683 us; speedup 1.0000x reference)
//
#include <hip/hip_runtime.h>

#define TBINS 256
#define EPS_F 1e-7f
#define INV_SIGMA 2.0f   // 1/0.5

// ---------------- zero workspace ----------------
__global__ void zero_ws_kernel(float* ws, int n) {
    int i = blockIdx.x * blockDim.x + threadIdx.x;
    int stride = gridDim.x * blockDim.x;
    for (; i < n; i += stride) ws[i] = 0.0f;
}

// ---------------- per-row kernel ----------------
// one 64-lane wave per row; block = 256 threads = 4 rows
__global__ __launch_bounds__(256) void row_kernel(
    const float* __restrict__ hz, const int* __restrict__ dur,
    const int* __restrict__ ev,  const int* __restrict__ lab,
    float* __restrict__ G, float* __restrict__ G0,
    float* __restrict__ rowA, float* __restrict__ acc, int n)
{
    const int wid  = threadIdx.x >> 6;
    const int lane = threadIdx.x & 63;
    const int row  = blockIdx.x * 4 + wid;
    if (row >= n) return;

    const float4* hv = (const float4*)(hz + (size_t)row * TBINS);
    float4 v = hv[lane];                      // elements 4*lane .. 4*lane+3

    // row max (phi includes a padded 0 column -> gamma = max(rowmax, 0))
    float m = fmaxf(fmaxf(v.x, v.y), fmaxf(v.z, v.w));
    #pragma unroll
    for (int off = 32; off; off >>= 1) m = fmaxf(m, __shfl_xor(m, off));
    const float gamma = fmaxf(m, 0.0f);

    const float e0 = expf(v.x - gamma);
    const float e1 = expf(v.y - gamma);
    const float e2 = expf(v.z - gamma);
    const float e3 = expf(v.w - gamma);
    const float local = e0 + e1 + e2 + e3;

    // wave-wide inclusive scan of per-lane sums
    float pre = local;
    #pragma unroll
    for (int off = 1; off < 64; off <<= 1) {
        float t = __shfl_up(pre, off);
        if (lane >= off) pre += t;
    }
    const float excl  = pre - local;
    const float total = __shfl(pre, 63);
    const float sum_  = total + expf(-gamma);   // + padded column exp(0-gamma)

    // inclusive cumsums of this lane's 4 elements
    const float c0 = excl + e0;
    const float c1 = c0 + e1;
    const float c2 = c1 + e2;
    const float c3 = c2 + e3;

    const int L = lab[row];
    const int d = dur[row];
    const int e = ev[row];

    // cumsum at label column (inclusive), broadcast from owning lane
    const int sel = L & 3;
    float csel = (sel == 0) ? c0 : (sel == 1) ? c1 : (sel == 2) ? c2 : c3;
    const float cum_at = __shfl(csel, L >> 2);

    const float inv = 1.0f / sum_;

    // bin updates: G[t][d] += exp(2*cdf(t)); G0 too when ev==0
    const int t0 = lane * 4;
    const float w0 = expf(c0 * inv * INV_SIGMA);
    const float w1 = expf(c1 * inv * INV_SIGMA);
    const float w2 = expf(c2 * inv * INV_SIGMA);
    const float w3 = expf(c3 * inv * INV_SIGMA);
    atomicAdd(&G[(t0 + 0) * TBINS + d], w0);
    atomicAdd(&G[(t0 + 1) * TBINS + d], w1);
    atomicAdd(&G[(t0 + 2) * TBINS + d], w2);
    atomicAdd(&G[(t0 + 3) * TBINS + d], w3);
    if (e == 0) {
        atomicAdd(&G0[(t0 + 0) * TBINS + d], w0);
        atomicAdd(&G0[(t0 + 1) * TBINS + d], w1);
        atomicAdd(&G0[(t0 + 2) * TBINS + d], w2);
        atomicAdd(&G0[(t0 + 3) * TBINS + d], w3);
    }

    if (lane == 0) {
        const float phi_at = hz[(size_t)row * TBINS + L];
        const float evf = (float)e;
        const float part1 = (phi_at - gamma) * evf;
        const float part2 = -logf(fmaxf(sum_, 0.0f) + EPS_F);
        const float part3 = logf(fmaxf(sum_ - cum_at, 0.0f) + EPS_F) * (1.0f - evf);
        atomicAdd(&acc[0], -(part1 + part2 + part3));
        const float a = cum_at * inv;              // cdf[i, lab_i]
        rowA[row] = e ? expf(-a * INV_SIGMA) : 0.0f;
    }
}

// ---------------- suffix scan over durations, fold in G0 ----------------
// B[t][d] = sum_{d'>d} G[t][d'] + G0[t][d], stored in-place into G
__global__ void suffix_kernel(float* __restrict__ G, const float* __restrict__ G0)
{
    int t = blockIdx.x * blockDim.x + threadIdx.x;
    if (t >= TBINS) return;
    float s = 0.0f;
    for (int d = TBINS - 1; d >= 0; --d) {
        const int idx = t * TBINS + d;
        const float g = G[idx];
        G[idx] = s + G0[idx];
        s += g;
    }
}

// ---------------- rank-loss gather + reduce ----------------
__global__ __launch_bounds__(256) void rank_kernel(
    const int* __restrict__ dur, const int* __restrict__ ev,
    const int* __restrict__ lab, const float* __restrict__ rowA,
    const float* __restrict__ B, float* __restrict__ acc, int n)
{
    const int i = blockIdx.x * blockDim.x + threadIdx.x;
    float val = 0.0f;
    if (i < n && ev[i]) {
        val = rowA[i] * B[lab[i] * TBINS + dur[i]];
    }
    #pragma unroll
    for (int off = 32; off; off >>= 1) val += __shfl_xor(val, off);
    __shared__ float s[4];
    if ((threadIdx.x & 63) == 0) s[threadIdx.x >> 6] = val;
    __syncthreads();
    if (threadIdx.x == 0) atomicAdd(&acc[1], s[0] + s[1] + s[2] + s[3]);
}

// ---------------- final combine ----------------
__global__ void final_kernel(const float* __restrict__ acc, float* __restrict__ out, int n)
{
    const double nll = (double)acc[0] / (double)n;
    const double rl  = (double)acc[1] / ((double)n * (double)n);
    out[0] = (float)(0.5 * nll + 0.5 * rl);
}

extern "C" void kernel_launch(void* const* d_in, const int* in_sizes, int n_in,
                              void* d_out, int out_size, void* d_ws, size_t ws_size,
                              hipStream_t stream) {
    const float* hz  = (const float*)d_in[0];
    const int*   dur = (const int*)d_in[1];
    const int*   ev  = (const int*)d_in[2];
    const int*   lab = (const int*)d_in[3];
    float* out = (float*)d_out;

    const int n = in_sizes[1];                 // 8192

    float* G    = (float*)d_ws;                // 256*256
    float* G0   = G  + TBINS * TBINS;          // 256*256
    float* rowA = G0 + TBINS * TBINS;          // n
    float* acc  = rowA + n;                    // acc[0]=nll_sum, acc[1]=rank_sum

    const int zn = 2 * TBINS * TBINS + n + 2;
    zero_ws_kernel<<<256, 256, 0, stream>>>(G, zn);
    row_kernel<<<(n + 3) / 4, 256, 0, stream>>>(hz, dur, ev, lab, G, G0, rowA, acc, n);
    suffix_kernel<<<1, TBINS, 0, stream>>>(G, G0);
    rank_kernel<<<(n + 255) / 256, 256, 0, stream>>>(dur, ev, lab, rowA, G, acc, n);
    final_kernel<<<1, 1, 0, stream>>>(acc, out, n);
}

// Round 2
// 95.622 us; speedup vs baseline: 3.1236x; 3.1236x over previous
//
#include <hip/hip_runtime.h>

#define TBINS 256
#define EPS_F 1e-7f
#define INV_SIGMA 2.0f   // 1/0.5
#define RPB 16           // rows per block in row_kernel

// ---------------- zero accumulators ----------------
__global__ void zero_acc_kernel(float* acc) {
    if (threadIdx.x < 2) acc[threadIdx.x] = 0.0f;
}

// ---------------- per-row kernel ----------------
// 1024 threads = 16 waves = 16 rows. Computes per-row softmax-cumsum stats,
// writes W transposed (WT[t][i] = exp(2*cdf_i(t))) via LDS transpose.
__global__ __launch_bounds__(1024) void row_kernel(
    const float* __restrict__ hz, const int* __restrict__ dur,
    const int* __restrict__ ev,  const int* __restrict__ lab,
    float* __restrict__ WT, float* __restrict__ rowA,
    float* __restrict__ acc, int n)
{
    __shared__ float trs[RPB][260];   // +4 pad: 16B-aligned rows, spread banks
    __shared__ float nllred[RPB];

    const int wid  = threadIdx.x >> 6;
    const int lane = threadIdx.x & 63;
    const int row  = blockIdx.x * RPB + wid;
    const bool active = row < n;
    const int rrow = active ? row : 0;

    const float4* hv = (const float4*)(hz + (size_t)rrow * TBINS);
    float4 v = hv[lane];                      // elements 4*lane .. 4*lane+3

    // row max (phi includes a padded 0 column -> gamma = max(rowmax, 0))
    float m = fmaxf(fmaxf(v.x, v.y), fmaxf(v.z, v.w));
    #pragma unroll
    for (int off = 32; off; off >>= 1) m = fmaxf(m, __shfl_xor(m, off));
    const float gamma = fmaxf(m, 0.0f);

    const float e0 = expf(v.x - gamma);
    const float e1 = expf(v.y - gamma);
    const float e2 = expf(v.z - gamma);
    const float e3 = expf(v.w - gamma);
    const float local = e0 + e1 + e2 + e3;

    // wave-wide inclusive scan of per-lane sums
    float pre = local;
    #pragma unroll
    for (int off = 1; off < 64; off <<= 1) {
        float t = __shfl_up(pre, off);
        if (lane >= off) pre += t;
    }
    const float excl  = pre - local;
    const float total = __shfl(pre, 63);
    const float sum_  = total + expf(-gamma);   // + padded column exp(0-gamma)

    // inclusive cumsums of this lane's 4 elements
    const float c0 = excl + e0;
    const float c1 = c0 + e1;
    const float c2 = c1 + e2;
    const float c3 = c2 + e3;

    const int L = lab[rrow];
    const int d = dur[rrow];
    const int e = ev[rrow];
    (void)d;

    // cumsum at label column (inclusive), broadcast from owning lane
    const int sel = L & 3;
    float csel = (sel == 0) ? c0 : (sel == 1) ? c1 : (sel == 2) ? c2 : c3;
    const float cum_at = __shfl(csel, L >> 2);

    const float inv = 1.0f / sum_;

    // W values: exp(2*cdf(t)) for t = 4*lane .. 4*lane+3
    float4 w;
    w.x = expf(c0 * inv * INV_SIGMA);
    w.y = expf(c1 * inv * INV_SIGMA);
    w.z = expf(c2 * inv * INV_SIGMA);
    w.w = expf(c3 * inv * INV_SIGMA);
    *(float4*)&trs[wid][4 * lane] = w;

    // per-row NLL partial -> per-wave slot
    float nll_i = 0.0f;
    if (lane == 0) {
        if (active) {
            const float phi_at = hz[(size_t)row * TBINS + L];
            const float evf = (float)e;
            const float part1 = (phi_at - gamma) * evf;
            const float part2 = -logf(fmaxf(sum_, 0.0f) + EPS_F);
            const float part3 = logf(fmaxf(sum_ - cum_at, 0.0f) + EPS_F) * (1.0f - evf);
            nll_i = -(part1 + part2 + part3);
            const float a = cum_at * inv;              // cdf[i, lab_i]
            rowA[row] = e ? expf(-a * INV_SIGMA) : 0.0f;
        }
        nllred[wid] = nll_i;
    }
    __syncthreads();

    if (threadIdx.x == 0) {
        float s = 0.0f;
        #pragma unroll
        for (int k = 0; k < RPB; ++k) s += nllred[k];
        atomicAdd(&acc[0], s);
    }

    // transpose out: thread -> (t = tid>>2, q = tid&3), writes WT[t][ibase+4q .. +3]
    const int t  = threadIdx.x >> 2;
    const int q  = threadIdx.x & 3;
    const int i0 = blockIdx.x * RPB + 4 * q;
    if (i0 + 3 < n) {
        float4 o;
        o.x = trs[4 * q + 0][t];
        o.y = trs[4 * q + 1][t];
        o.z = trs[4 * q + 2][t];
        o.w = trs[4 * q + 3][t];
        *(float4*)&WT[(size_t)t * n + i0] = o;
    }
}

// ---------------- aggregation: histogram over dur + suffix scan ----------------
// one block per t. B[t][d] = sum_{d'>d} G[t][d'] + G0[t][d]
__global__ __launch_bounds__(1024) void agg_kernel(
    const float* __restrict__ WT, const int* __restrict__ dur,
    const int* __restrict__ ev, float* __restrict__ B, int n)
{
    __shared__ float binsG[TBINS];
    __shared__ float binsG0[TBINS];
    __shared__ float scan[TBINS];

    const int t   = blockIdx.x;
    const int tid = threadIdx.x;

    if (tid < TBINS) { binsG[tid] = 0.0f; binsG0[tid] = 0.0f; }
    __syncthreads();

    const float* w = WT + (size_t)t * n;
    for (int i = tid; i < n; i += 1024) {
        const float v = w[i];
        const int d = dur[i];
        atomicAdd(&binsG[d], v);
        if (ev[i] == 0) atomicAdd(&binsG0[d], v);
    }
    __syncthreads();

    // inclusive Hillis-Steele scan over binsG (256 lanes active)
    if (tid < TBINS) scan[tid] = binsG[tid];
    __syncthreads();
    for (int off = 1; off < TBINS; off <<= 1) {
        float add = 0.0f;
        if (tid < TBINS && tid >= off) add = scan[tid - off];
        __syncthreads();
        if (tid < TBINS) scan[tid] += add;
        __syncthreads();
    }
    if (tid < TBINS) {
        const float total = scan[TBINS - 1];
        const float suffix = total - scan[tid];      // sum over d' > tid
        B[t * TBINS + tid] = suffix + binsG0[tid];
    }
}

// ---------------- rank-loss gather + reduce ----------------
__global__ __launch_bounds__(256) void rank_kernel(
    const int* __restrict__ dur, const int* __restrict__ ev,
    const int* __restrict__ lab, const float* __restrict__ rowA,
    const float* __restrict__ B, float* __restrict__ acc, int n)
{
    const int i = blockIdx.x * blockDim.x + threadIdx.x;
    float val = 0.0f;
    if (i < n && ev[i]) {
        val = rowA[i] * B[lab[i] * TBINS + dur[i]];
    }
    #pragma unroll
    for (int off = 32; off; off >>= 1) val += __shfl_xor(val, off);
    __shared__ float s[4];
    if ((threadIdx.x & 63) == 0) s[threadIdx.x >> 6] = val;
    __syncthreads();
    if (threadIdx.x == 0) atomicAdd(&acc[1], s[0] + s[1] + s[2] + s[3]);
}

// ---------------- final combine ----------------
__global__ void final_kernel(const float* __restrict__ acc, float* __restrict__ out, int n)
{
    const double nll = (double)acc[0] / (double)n;
    const double rl  = (double)acc[1] / ((double)n * (double)n);
    out[0] = (float)(0.5 * nll + 0.5 * rl);
}

extern "C" void kernel_launch(void* const* d_in, const int* in_sizes, int n_in,
                              void* d_out, int out_size, void* d_ws, size_t ws_size,
                              hipStream_t stream) {
    const float* hz  = (const float*)d_in[0];
    const int*   dur = (const int*)d_in[1];
    const int*   ev  = (const int*)d_in[2];
    const int*   lab = (const int*)d_in[3];
    float* out = (float*)d_out;

    const int n = in_sizes[1];                 // 8192

    float* WT   = (float*)d_ws;                // [TBINS][n]  (8 MB)
    float* B    = WT + (size_t)TBINS * n;      // [TBINS][TBINS]
    float* rowA = B + TBINS * TBINS;           // [n]
    float* acc  = rowA + n;                    // acc[0]=nll_sum, acc[1]=rank_sum

    zero_acc_kernel<<<1, 64, 0, stream>>>(acc);
    row_kernel<<<(n + RPB - 1) / RPB, 1024, 0, stream>>>(hz, dur, ev, lab, WT, rowA, acc, n);
    agg_kernel<<<TBINS, 1024, 0, stream>>>(WT, dur, ev, B, n);
    rank_kernel<<<(n + 255) / 256, 256, 0, stream>>>(dur, ev, lab, rowA, B, acc, n);
    final_kernel<<<1, 1, 0, stream>>>(acc, out, n);
}